// Round 1
// baseline (109.978 us; speedup 1.0000x reference)
//
#include <hip/hip_runtime.h>
#include <hip/hip_bf16.h>
#include <math.h>

typedef unsigned short u16;
typedef __attribute__((ext_vector_type(8))) short short8;
typedef __attribute__((ext_vector_type(4))) float f32x4;

__device__ __forceinline__ u16 f2bf(float f) {
  union { __hip_bfloat16 h; u16 u; } c;
  c.h = __float2bfloat16(f);
  return c.u;
}

// ---------------- prep: transpose+scale Q,K -> ws [bh][seq][64] bf16 ----------------
// grid (32 t-tiles, 32 bh, 2 {q,k}), block 256
__global__ __launch_bounds__(256) void prep_qk(const float* __restrict__ qkv,
                                               u16* __restrict__ wsQ,
                                               u16* __restrict__ wsK) {
  __shared__ float tile[64 * 67];
  const int tid = threadIdx.x;
  const int t0 = blockIdx.x * 64;
  const int bh = blockIdx.y;
  const int b = bh >> 3, h = bh & 7;
  const int isK = blockIdx.z;
  const float scale = 0.35355339059327378f;  // 64^-0.25
  const size_t inbase = ((size_t)b * 1536 + (size_t)isK * 512 + (size_t)h * 64) * 2048;

  const int c = tid >> 2, tq = tid & 3;
#pragma unroll
  for (int u = 0; u < 4; ++u) {
    const int t = tq * 16 + u * 4;
    const float4 v = *(const float4*)(qkv + inbase + (size_t)c * 2048 + t0 + t);
    tile[c * 67 + t + 0] = v.x * scale;
    tile[c * 67 + t + 1] = v.y * scale;
    tile[c * 67 + t + 2] = v.z * scale;
    tile[c * 67 + t + 3] = v.w * scale;
  }
  __syncthreads();
  const int tt = tid >> 2, cq = tid & 3, c0 = cq * 16;
  u16* dst = (isK ? wsK : wsQ) + ((size_t)bh * 2048 + t0 + tt) * 64 + c0;
  union { u16 us[8]; uint4 v; } p0, p1;
#pragma unroll
  for (int i = 0; i < 8; ++i) p0.us[i] = f2bf(tile[(c0 + i) * 67 + tt]);
#pragma unroll
  for (int i = 0; i < 8; ++i) p1.us[i] = f2bf(tile[(c0 + 8 + i) * 67 + tt]);
  *(uint4*)(dst) = p0.v;
  *(uint4*)(dst + 8) = p1.v;
}

// ---------------- prep: convert V -> ws [bh][c][seq] bf16 ----------------
// grid 4096, block 256 : one float4 per thread
__global__ __launch_bounds__(256) void prep_v(const float* __restrict__ qkv,
                                              u16* __restrict__ wsV) {
  const int idx = blockIdx.x * 256 + threadIdx.x;
  const int s4 = idx & 511;          // 2048/4 float4 per row
  const int cc = (idx >> 9) & 63;
  const int bh = idx >> 15;
  const int b = bh >> 3, h = bh & 7;
  const float4 v = *(const float4*)(qkv + (((size_t)b * 1536 + 1024 + (size_t)h * 64 + cc) * 2048) + (size_t)s4 * 4);
  union { u16 us[4]; uint2 d; } pk;
  pk.us[0] = f2bf(v.x); pk.us[1] = f2bf(v.y); pk.us[2] = f2bf(v.z); pk.us[3] = f2bf(v.w);
  *(uint2*)(wsV + ((size_t)bh * 64 + cc) * 2048 + (size_t)s4 * 4) = pk.d;
}

// ---------------- fused flash attention ----------------
// grid (32 t-blocks, 32 bh), block 256 (4 waves, 16 t-rows each)
__global__ __launch_bounds__(256, 3) void attn_kernel(const u16* __restrict__ wsQ,
                                                      const u16* __restrict__ wsK,
                                                      const u16* __restrict__ wsV,
                                                      float* __restrict__ out) {
  __shared__ __align__(16) u16 Qs[64 * 64];   // [t][c] swizzled
  __shared__ __align__(16) u16 Ks[64 * 64];   // [s][c] swizzled
  __shared__ __align__(16) u16 Vs[64 * 64];   // [c][s] swizzled
  __shared__ float Ps[4][16 * 65];            // per-wave P rows (stride 65)

  const int tid = threadIdx.x;
  const int w = tid >> 6;
  const int lane = tid & 63;
  const int tl = lane & 15;
  const int g = lane >> 4;
  const int bh = blockIdx.y;
  const int t0 = blockIdx.x * 64;

  const u16* qb = wsQ + (size_t)bh * (2048 * 64);
  const u16* kb = wsK + (size_t)bh * (2048 * 64);
  const u16* vb = wsV + (size_t)bh * (2048 * 64);

  // stage Q tile [64 t][64 c], swizzle byte ^= (row&7)<<4 via inverse-swizzled source granule
#pragma unroll
  for (int it = 0; it < 2; ++it) {
    const int o = (it * 256 + tid) * 16;  // LDS byte offset (linear)
    const int row = o >> 7;
    const int gl = (o >> 4) & 7;
    const u16* src = qb + (size_t)(t0 + row) * 64 + ((gl ^ (row & 7)) << 3);
    *(uint4*)((char*)Qs + o) = *(const uint4*)src;
  }

  float m_run = -__builtin_inff();
  float l_run = 0.0f;
  const f32x4 zero4 = {0.f, 0.f, 0.f, 0.f};
  f32x4 acc_o[4];
#pragma unroll
  for (int i = 0; i < 4; ++i) acc_o[i] = zero4;

  float* Pw = &Ps[w][0];

  for (int sb = 0; sb < 2048; sb += 64) {
    __syncthreads();  // protect Ks/Vs (and Qs on iter 0)
#pragma unroll
    for (int it = 0; it < 2; ++it) {      // stage K tile [64 s][64 c]
      const int o = (it * 256 + tid) * 16;
      const int row = o >> 7;
      const int gl = (o >> 4) & 7;
      const u16* src = kb + (size_t)(sb + row) * 64 + ((gl ^ (row & 7)) << 3);
      *(uint4*)((char*)Ks + o) = *(const uint4*)src;
    }
#pragma unroll
    for (int it = 0; it < 2; ++it) {      // stage V tile [64 c][64 s]
      const int o = (it * 256 + tid) * 16;
      const int row = o >> 7;             // c
      const int gl = (o >> 4) & 7;
      const u16* src = vb + (size_t)row * 2048 + sb + ((gl ^ (row & 7)) << 3);
      *(uint4*)((char*)Vs + o) = *(const uint4*)src;
    }
    __syncthreads();

    // Q fragments (B operand): Q[t=w*16+tl][c = kk*32+8g .. +7]
    short8 qf[2];
#pragma unroll
    for (int kk = 0; kk < 2; ++kk) {
      const int row = w * 16 + tl;
      const int byteoff = row * 128 + (((kk * 32 + 8 * g) * 2) ^ ((row & 7) << 4));
      qf[kk] = *(const short8*)((const char*)Qs + byteoff);
    }

    // S^T = K * Q  (D[s][t]: lane holds S[t=tl][s = mt*16 + 4g + j])
    f32x4 sacc[4];
#pragma unroll
    for (int mt = 0; mt < 4; ++mt) sacc[mt] = zero4;
#pragma unroll
    for (int mt = 0; mt < 4; ++mt) {
#pragma unroll
      for (int kk = 0; kk < 2; ++kk) {
        const int row = mt * 16 + tl;
        const int byteoff = row * 128 + (((kk * 32 + 8 * g) * 2) ^ ((row & 7) << 4));
        const short8 kf = *(const short8*)((const char*)Ks + byteoff);
        sacc[mt] = __builtin_amdgcn_mfma_f32_16x16x32_bf16(kf, qf[kk], sacc[mt], 0, 0, 0);
      }
    }

    // online softmax; row t = tl is per-lane uniform
    float bm = -__builtin_inff();
#pragma unroll
    for (int mt = 0; mt < 4; ++mt)
#pragma unroll
      for (int j = 0; j < 4; ++j) bm = fmaxf(bm, sacc[mt][j]);
    bm = fmaxf(bm, __shfl_xor(bm, 16, 64));
    bm = fmaxf(bm, __shfl_xor(bm, 32, 64));

    const float mnew = fmaxf(m_run, bm);
    const float corr = __expf(m_run - mnew);
    float p[4][4];
    float psum = 0.f;
#pragma unroll
    for (int mt = 0; mt < 4; ++mt)
#pragma unroll
      for (int j = 0; j < 4; ++j) {
        const float e = __expf(sacc[mt][j] - mnew);
        p[mt][j] = e;
        psum += e;
      }
    psum += __shfl_xor(psum, 16, 64);
    psum += __shfl_xor(psum, 32, 64);
    l_run = l_run * corr + psum;
    m_run = mnew;
#pragma unroll
    for (int mc = 0; mc < 4; ++mc) acc_o[mc] *= corr;

    // P -> per-wave LDS (f32, stride 65); wave-private, no barrier needed
#pragma unroll
    for (int mt = 0; mt < 4; ++mt)
#pragma unroll
      for (int j = 0; j < 4; ++j)
        Pw[tl * 65 + mt * 16 + 4 * g + j] = p[mt][j];

    // PV: O[c][t] += V[c][s] * P^T[s][t]
#pragma unroll
    for (int kk2 = 0; kk2 < 2; ++kk2) {
      union { u16 us[8]; short8 v; } pf;
#pragma unroll
      for (int jb = 0; jb < 8; ++jb)
        pf.us[jb] = f2bf(Pw[tl * 65 + kk2 * 32 + 8 * g + jb]);
#pragma unroll
      for (int mc = 0; mc < 4; ++mc) {
        const int row = mc * 16 + tl;  // c
        const int byteoff = row * 128 + (((kk2 * 32 + 8 * g) * 2) ^ ((row & 7) << 4));
        const short8 vf = *(const short8*)((const char*)Vs + byteoff);
        acc_o[mc] = __builtin_amdgcn_mfma_f32_16x16x32_bf16(vf, pf.v, acc_o[mc], 0, 0, 0);
      }
    }
  }

  // epilogue: divide by l, store f32 out[bh*64 + c][t]
  const float inv = 1.0f / l_run;
  const int tg = t0 + w * 16 + tl;
  const size_t obase = (size_t)bh * 64 * 2048;
#pragma unroll
  for (int mc = 0; mc < 4; ++mc)
#pragma unroll
    for (int j = 0; j < 4; ++j) {
      const int c = mc * 16 + 4 * g + j;
      out[obase + (size_t)c * 2048 + tg] = acc_o[mc][j] * inv;
    }
}

extern "C" void kernel_launch(void* const* d_in, const int* in_sizes, int n_in,
                              void* d_out, int out_size, void* d_ws, size_t ws_size,
                              hipStream_t stream) {
  const float* qkv = (const float*)d_in[0];
  float* out = (float*)d_out;
  u16* wsQ = (u16*)d_ws;
  u16* wsK = wsQ + (size_t)32 * 2048 * 64;
  u16* wsV = wsK + (size_t)32 * 2048 * 64;

  prep_qk<<<dim3(32, 32, 2), 256, 0, stream>>>(qkv, wsQ, wsK);
  prep_v<<<4096, 256, 0, stream>>>(qkv, wsV);
  attn_kernel<<<dim3(32, 32), 256, 0, stream>>>(wsQ, wsK, wsV, out);
}

// Round 3
// 108.272 us; speedup vs baseline: 1.0158x; 1.0158x over previous
//
#include <hip/hip_runtime.h>
#include <hip/hip_bf16.h>

typedef unsigned short u16;
typedef unsigned int u32;
typedef __attribute__((ext_vector_type(8))) short short8;
typedef __attribute__((ext_vector_type(16))) float f32x16;

#define SEQ 2048

__device__ __forceinline__ u16 f2bf(float f) {
  union { __hip_bfloat16 h; u16 u; } c;
  c.h = __float2bfloat16(f);
  return c.u;
}

__device__ __forceinline__ float exp2fast(float x) {
  return __builtin_amdgcn_exp2f(x);  // v_exp_f32 (base-2)
}

// ---------------- prep: transpose+scale Q,K -> ws [bh][seq][64] bf16 ----------------
// scale = 64^-0.25 * sqrt(log2(e))  (exp2-domain softmax)
__global__ __launch_bounds__(256) void prep_qk(const float* __restrict__ qkv,
                                               u16* __restrict__ wsQ,
                                               u16* __restrict__ wsK) {
  __shared__ float tile[64 * 67];
  const int tid = threadIdx.x;
  const int t0 = blockIdx.x * 64;
  const int bh = blockIdx.y;
  const int b = bh >> 3, h = bh & 7;
  const int isK = blockIdx.z;
  const float scale = 0.42466090014692505f;  // 64^-0.25 * sqrt(log2 e)
  const size_t inbase = ((size_t)b * 1536 + (size_t)isK * 512 + (size_t)h * 64) * SEQ;

  const int c = tid >> 2, tq = tid & 3;
#pragma unroll
  for (int u = 0; u < 4; ++u) {
    const int t = tq * 16 + u * 4;
    const float4 v = *(const float4*)(qkv + inbase + (size_t)c * SEQ + t0 + t);
    tile[c * 67 + t + 0] = v.x * scale;
    tile[c * 67 + t + 1] = v.y * scale;
    tile[c * 67 + t + 2] = v.z * scale;
    tile[c * 67 + t + 3] = v.w * scale;
  }
  __syncthreads();
  const int tt = tid >> 2, cq = tid & 3, c0 = cq * 16;
  u16* dst = (isK ? wsK : wsQ) + ((size_t)bh * SEQ + t0 + tt) * 64 + c0;
  union { u16 us[8]; uint4 v; } p0, p1;
#pragma unroll
  for (int i = 0; i < 8; ++i) p0.us[i] = f2bf(tile[(c0 + i) * 67 + tt]);
#pragma unroll
  for (int i = 0; i < 8; ++i) p1.us[i] = f2bf(tile[(c0 + 8 + i) * 67 + tt]);
  *(uint4*)(dst) = p0.v;
  *(uint4*)(dst + 8) = p1.v;
}

// ---------------- prep: convert V -> ws [bh][c][seq] bf16 ----------------
__global__ __launch_bounds__(256) void prep_v(const float* __restrict__ qkv,
                                              u16* __restrict__ wsV) {
  const int idx = blockIdx.x * 256 + threadIdx.x;
  const int s4 = idx & 511;
  const int cc = (idx >> 9) & 63;
  const int bh = idx >> 15;
  const int b = bh >> 3, h = bh & 7;
  const float4 v = *(const float4*)(qkv + (((size_t)b * 1536 + 1024 + (size_t)h * 64 + cc) * SEQ) + (size_t)s4 * 4);
  union { u16 us[4]; uint2 d; } pk;
  pk.us[0] = f2bf(v.x); pk.us[1] = f2bf(v.y); pk.us[2] = f2bf(v.z); pk.us[3] = f2bf(v.w);
  *(uint2*)(wsV + ((size_t)bh * 64 + cc) * SEQ + (size_t)s4 * 4) = pk.d;
}

// ---------------- fused flash attention: 4 waves x QBLK=32, KVBLK=64 ----------------
// grid 512 linear (xcd-swizzled to tb in 0..15, bh in 0..31), block 256
__global__ __launch_bounds__(256, 2) void attn_kernel(const u16* __restrict__ wsQ,
                                                      const u16* __restrict__ wsK,
                                                      const u16* __restrict__ wsV,
                                                      float* __restrict__ out) {
  __shared__ __align__(16) u16 Ks[64 * 64];  // [s][c], XOR-granule swizzled
  __shared__ __align__(16) u16 Vs[64 * 64];  // [c][s], XOR-granule swizzled

  const int tid = threadIdx.x;
  const int w = tid >> 6;
  const int lane = tid & 63;
  const int tl = lane & 31;
  const int hi = lane >> 5;

  // XCD swizzle: 64 consecutive virtual blocks (4 bh) per XCD
  const int bid = blockIdx.x;
  const int vb = (bid & 7) * 64 + (bid >> 3);
  const int tb = vb & 15, bh = vb >> 4;
  const int t0 = tb * 128;

  const u16* qb = wsQ + (size_t)bh * (SEQ * 64);
  const u16* kb = wsK + (size_t)bh * (SEQ * 64);
  const u16* vb_ = wsV + (size_t)bh * (SEQ * 64);

  // Q fragments in registers (B-operand): Q[t = t0+w*32+tl][c = 16ks+8hi+e]
  short8 qf[4];
  {
    const u16* qrow = qb + (size_t)(t0 + w * 32 + tl) * 64 + 8 * hi;
#pragma unroll
    for (int ks = 0; ks < 4; ++ks) qf[ks] = *(const short8*)(qrow + 16 * ks);
  }

  // ---- prologue: stage tile 0 ----
  uint4 kreg[2], vreg[2];
#pragma unroll
  for (int it = 0; it < 2; ++it) {
    const int idx = it * 256 + tid;
    const int row = idx >> 3, g = idx & 7;
    kreg[it] = *(const uint4*)(kb + (size_t)row * 64 + g * 8);
    vreg[it] = *(const uint4*)(vb_ + (size_t)row * SEQ + g * 8);
  }
#pragma unroll
  for (int it = 0; it < 2; ++it) {
    const int idx = it * 256 + tid;
    const int row = idx >> 3, g = idx & 7;
    *(uint4*)((char*)Ks + row * 128 + ((g ^ (row & 7)) << 4)) = kreg[it];
    *(uint4*)((char*)Vs + row * 128 + ((g ^ (row & 7)) << 4)) = vreg[it];
  }
  __syncthreads();

  float m_run = -__builtin_inff();
  float l_run = 0.0f;
  f32x16 acc[2];
#pragma unroll
  for (int ct = 0; ct < 2; ++ct)
#pragma unroll
    for (int r = 0; r < 16; ++r) acc[ct][r] = 0.0f;

  for (int i = 0; i < 32; ++i) {
    // T14: issue next-tile global loads early (hidden under compute)
    const int sbn = ((i + 1) & 31) << 6;
#pragma unroll
    for (int it = 0; it < 2; ++it) {
      const int idx = it * 256 + tid;
      const int row = idx >> 3, g = idx & 7;
      kreg[it] = *(const uint4*)(kb + (size_t)(sbn + row) * 64 + g * 8);
      vreg[it] = *(const uint4*)(vb_ + (size_t)row * SEQ + sbn + g * 8);
    }

    // ---- compute current tile: 2 sub-tiles of 32 s ----
#pragma unroll
    for (int ss = 0; ss < 2; ++ss) {
      // QK^T (swapped): D[s][t], lane owns col t=tl, rows s=(r&3)+8*(r>>2)+4*hi
      f32x16 sacc = {0, 0, 0, 0, 0, 0, 0, 0, 0, 0, 0, 0, 0, 0, 0, 0};
#pragma unroll
      for (int ks = 0; ks < 4; ++ks) {
        const int row = ss * 32 + tl;
        const int gr = 2 * ks + hi;
        const short8 kf = *(const short8*)((const char*)Ks + row * 128 + ((gr ^ (row & 7)) << 4));
        sacc = __builtin_amdgcn_mfma_f32_32x32x16_bf16(kf, qf[ks], sacc, 0, 0, 0);
      }

      // row max (tree) + cross-half combine
      float mx[8];
#pragma unroll
      for (int r = 0; r < 8; ++r) mx[r] = fmaxf(sacc[2 * r], sacc[2 * r + 1]);
#pragma unroll
      for (int r = 0; r < 4; ++r) mx[r] = fmaxf(mx[r], mx[r + 4]);
      mx[0] = fmaxf(mx[0], mx[2]);
      mx[1] = fmaxf(mx[1], mx[3]);
      float bm = fmaxf(mx[0], mx[1]);
      bm = fmaxf(bm, __shfl_xor(bm, 32, 64));

      // T13 defer-rescale (base-2 domain, THR=8 -> P <= 256)
      if (!__all(bm - m_run <= 8.0f)) {
        const float mnew = fmaxf(m_run, bm);
        const float corr = exp2fast(m_run - mnew);
        m_run = mnew;
        l_run *= corr;
#pragma unroll
        for (int ct = 0; ct < 2; ++ct)
#pragma unroll
          for (int r = 0; r < 16; ++r) acc[ct][r] *= corr;
      }

      float p[16];
      float ps[8];
#pragma unroll
      for (int r = 0; r < 16; ++r) p[r] = exp2fast(sacc[r] - m_run);
#pragma unroll
      for (int r = 0; r < 8; ++r) ps[r] = p[2 * r] + p[2 * r + 1];
#pragma unroll
      for (int r = 0; r < 4; ++r) ps[r] += ps[r + 4];
      float psum = (ps[0] + ps[2]) + (ps[1] + ps[3]);
      psum += __shfl_xor(psum, 32, 64);
      l_run += psum;

      // pack P to bf16 pairs; own pair i covers s = {(0,1),(2,3),(8,9),(10,11),
      // (16,17),(18,19),(24,25),(26,27)}[i] + 4*hi
      u32 pk[8];
#pragma unroll
      for (int q2 = 0; q2 < 8; ++q2)
        pk[q2] = (u32)f2bf(p[2 * q2]) | ((u32)f2bf(p[2 * q2 + 1]) << 16);
      // T12: permlane32_swap assembles B-operand k-order (lo lanes k=0..7, hi k=8..15)
      asm volatile("v_permlane32_swap_b32 %0, %1" : "+v"(pk[0]), "+v"(pk[2]));
      asm volatile("v_permlane32_swap_b32 %0, %1" : "+v"(pk[1]), "+v"(pk[3]));
      asm volatile("v_permlane32_swap_b32 %0, %1" : "+v"(pk[4]), "+v"(pk[6]));
      asm volatile("v_permlane32_swap_b32 %0, %1" : "+v"(pk[5]), "+v"(pk[7]));
      union { u32 u[4]; short8 v; } pf0, pf1;
      pf0.u[0] = pk[0]; pf0.u[1] = pk[1]; pf0.u[2] = pk[2]; pf0.u[3] = pk[3];
      pf1.u[0] = pk[4]; pf1.u[1] = pk[5]; pf1.u[2] = pk[6]; pf1.u[3] = pk[7];

      // PV: O^T[c][t] += V^T[c][s] * P^T[s][t]
#pragma unroll
      for (int ct = 0; ct < 2; ++ct) {
#pragma unroll
        for (int ks2 = 0; ks2 < 2; ++ks2) {
          const int row = ct * 32 + tl;
          const int gr = ss * 4 + 2 * ks2 + hi;
          const short8 vf = *(const short8*)((const char*)Vs + row * 128 + ((gr ^ (row & 7)) << 4));
          acc[ct] = __builtin_amdgcn_mfma_f32_32x32x16_bf16(vf, ks2 ? pf1.v : pf0.v, acc[ct], 0, 0, 0);
        }
      }
    }

    // commit staged tile
    __syncthreads();
#pragma unroll
    for (int it = 0; it < 2; ++it) {
      const int idx = it * 256 + tid;
      const int row = idx >> 3, g = idx & 7;
      *(uint4*)((char*)Ks + row * 128 + ((g ^ (row & 7)) << 4)) = kreg[it];
      *(uint4*)((char*)Vs + row * 128 + ((g ^ (row & 7)) << 4)) = vreg[it];
    }
    __syncthreads();
  }

  // epilogue: O[c][t] = acc/l
  const float inv = 1.0f / l_run;
  const int t = t0 + w * 32 + tl;
  float* ob = out + (size_t)bh * 64 * SEQ + t;
#pragma unroll
  for (int ct = 0; ct < 2; ++ct)
#pragma unroll
    for (int r = 0; r < 16; ++r) {
      const int c = ct * 32 + (r & 3) + 8 * (r >> 2) + 4 * hi;
      ob[(size_t)c * SEQ] = acc[ct][r] * inv;
    }
}

extern "C" void kernel_launch(void* const* d_in, const int* in_sizes, int n_in,
                              void* d_out, int out_size, void* d_ws, size_t ws_size,
                              hipStream_t stream) {
  const float* qkv = (const float*)d_in[0];
  float* out = (float*)d_out;
  u16* wsQ = (u16*)d_ws;
  u16* wsK = wsQ + (size_t)32 * SEQ * 64;
  u16* wsV = wsK + (size_t)32 * SEQ * 64;

  prep_qk<<<dim3(32, 32, 2), 256, 0, stream>>>(qkv, wsQ, wsK);
  prep_v<<<4096, 256, 0, stream>>>(qkv, wsV);
  attn_kernel<<<512, 256, 0, stream>>>(wsQ, wsK, wsV, out);
}

// Round 4
// 84.862 us; speedup vs baseline: 1.2960x; 1.2759x over previous
//
#include <hip/hip_runtime.h>
#include <hip/hip_bf16.h>

typedef unsigned short u16;
typedef unsigned int u32;
typedef __attribute__((ext_vector_type(8))) short short8;
typedef __attribute__((ext_vector_type(16))) float f32x16;

#define SEQ 2048

__device__ __forceinline__ u16 f2bf(float f) {
  union { __hip_bfloat16 h; u16 u; } c;
  c.h = __float2bfloat16(f);
  return c.u;
}

__device__ __forceinline__ float exp2fast(float x) {
  return __builtin_amdgcn_exp2f(x);  // v_exp_f32 (base-2)
}

// ---------------- prep: transpose+scale Q,K -> ws [bh][seq][64] bf16 ----------------
// scale = 64^-0.25 * sqrt(log2(e))  (exp2-domain softmax)
__global__ __launch_bounds__(256) void prep_qk(const float* __restrict__ qkv,
                                               u16* __restrict__ wsQ,
                                               u16* __restrict__ wsK) {
  __shared__ float tile[64 * 67];
  const int tid = threadIdx.x;
  const int t0 = blockIdx.x * 64;
  const int bh = blockIdx.y;
  const int b = bh >> 3, h = bh & 7;
  const int isK = blockIdx.z;
  const float scale = 0.42466090014692505f;  // 64^-0.25 * sqrt(log2 e)
  const size_t inbase = ((size_t)b * 1536 + (size_t)isK * 512 + (size_t)h * 64) * SEQ;

  const int c = tid >> 2, tq = tid & 3;
#pragma unroll
  for (int u = 0; u < 4; ++u) {
    const int t = tq * 16 + u * 4;
    const float4 v = *(const float4*)(qkv + inbase + (size_t)c * SEQ + t0 + t);
    tile[c * 67 + t + 0] = v.x * scale;
    tile[c * 67 + t + 1] = v.y * scale;
    tile[c * 67 + t + 2] = v.z * scale;
    tile[c * 67 + t + 3] = v.w * scale;
  }
  __syncthreads();
  const int tt = tid >> 2, cq = tid & 3, c0 = cq * 16;
  u16* dst = (isK ? wsK : wsQ) + ((size_t)bh * SEQ + t0 + tt) * 64 + c0;
  union { u16 us[8]; uint4 v; } p0, p1;
#pragma unroll
  for (int i = 0; i < 8; ++i) p0.us[i] = f2bf(tile[(c0 + i) * 67 + tt]);
#pragma unroll
  for (int i = 0; i < 8; ++i) p1.us[i] = f2bf(tile[(c0 + 8 + i) * 67 + tt]);
  *(uint4*)(dst) = p0.v;
  *(uint4*)(dst + 8) = p1.v;
}

// ---------------- prep: convert V -> ws [bh][c][seq] bf16 ----------------
__global__ __launch_bounds__(256) void prep_v(const float* __restrict__ qkv,
                                              u16* __restrict__ wsV) {
  const int idx = blockIdx.x * 256 + threadIdx.x;
  const int s4 = idx & 511;
  const int cc = (idx >> 9) & 63;
  const int bh = idx >> 15;
  const int b = bh >> 3, h = bh & 7;
  const float4 v = *(const float4*)(qkv + (((size_t)b * 1536 + 1024 + (size_t)h * 64 + cc) * SEQ) + (size_t)s4 * 4);
  union { u16 us[4]; uint2 d; } pk;
  pk.us[0] = f2bf(v.x); pk.us[1] = f2bf(v.y); pk.us[2] = f2bf(v.z); pk.us[3] = f2bf(v.w);
  *(uint2*)(wsV + ((size_t)bh * 64 + cc) * SEQ + (size_t)s4 * 4) = pk.d;
}

// ---------------- fused flash attention, barrier-free main loop ----------------
// block = 256 thr = 4 waves = 2 t-units x 2 s-halves. Each wave: QBLK=64 (2 col-blocks),
// s-range 1024 (16 iters of 64). K/V fragments loaded directly from L2 (no LDS staging).
// grid 512 (XCD-swizzled): bh = vb>>4, tb-pair = vb&15.
__global__ __launch_bounds__(256, 2) void attn_kernel(const u16* __restrict__ wsQ,
                                                      const u16* __restrict__ wsK,
                                                      const u16* __restrict__ wsV,
                                                      float* __restrict__ out) {
  __shared__ float Xacc[2][64 * 64];      // [unit][(cb*2+ct)*16+r][lane] partials from sh1
  __shared__ float Xml[2][2][2][32];      // [unit][cb][m0/l1][tl]

  const int tid = threadIdx.x;
  const int w = tid >> 6;
  const int lane = tid & 63;
  const int tl = lane & 31;
  const int hi = lane >> 5;
  const int unit = w >> 1;                // 0,1 : which 64-t unit
  const int sh = w & 1;                   // 0,1 : which s-half

  const int bid = blockIdx.x;
  const int vb = (bid & 7) * 64 + (bid >> 3);
  const int tbp = vb & 15, bh = vb >> 4;
  const int tq0 = tbp * 128 + unit * 64;  // base t of this wave's 64 columns

  const u16* qb = wsQ + (size_t)bh * (SEQ * 64);
  const u16* kb = wsK + (size_t)bh * (SEQ * 64);
  const u16* vbp = wsV + (size_t)bh * (SEQ * 64);

  // Q fragments: qf[cb][ks] = Q[t=tq0+cb*32+tl][c=16ks+8hi .. +7]
  short8 qf[2][4];
#pragma unroll
  for (int cb = 0; cb < 2; ++cb) {
    const u16* qrow = qb + (size_t)(tq0 + cb * 32 + tl) * 64 + 8 * hi;
#pragma unroll
    for (int ks = 0; ks < 4; ++ks) qf[cb][ks] = *(const short8*)(qrow + 16 * ks);
  }

  float m[2] = {-__builtin_inff(), -__builtin_inff()};
  float l[2] = {0.f, 0.f};
  f32x16 acc[2][2];
#pragma unroll
  for (int cb = 0; cb < 2; ++cb)
#pragma unroll
    for (int ct = 0; ct < 2; ++ct)
#pragma unroll
      for (int r = 0; r < 16; ++r) acc[cb][ct][r] = 0.0f;

  const int s_base = sh * 1024;
  for (int it = 0; it < 16; ++it) {
    const int s0 = s_base + it * 64;
#pragma unroll
    for (int ss = 0; ss < 2; ++ss) {
      // K fragments direct from global/L2: K[s=s0+ss*32+tl][c=16ks+8hi..]
      const u16* krow = kb + (size_t)(s0 + ss * 32 + tl) * 64 + 8 * hi;
      short8 kf[4];
#pragma unroll
      for (int ks = 0; ks < 4; ++ks) kf[ks] = *(const short8*)(krow + 16 * ks);

      f32x16 sacc[2];
#pragma unroll
      for (int cb = 0; cb < 2; ++cb)
#pragma unroll
        for (int r = 0; r < 16; ++r) sacc[cb][r] = 0.0f;
#pragma unroll
      for (int ks = 0; ks < 4; ++ks) {
        sacc[0] = __builtin_amdgcn_mfma_f32_32x32x16_bf16(kf[ks], qf[0][ks], sacc[0], 0, 0, 0);
        sacc[1] = __builtin_amdgcn_mfma_f32_32x32x16_bf16(kf[ks], qf[1][ks], sacc[1], 0, 0, 0);
      }

      // per-cb block max
      float bm[2];
#pragma unroll
      for (int cb = 0; cb < 2; ++cb) {
        float mx[8];
#pragma unroll
        for (int r = 0; r < 8; ++r) mx[r] = fmaxf(sacc[cb][2 * r], sacc[cb][2 * r + 1]);
#pragma unroll
        for (int r = 0; r < 4; ++r) mx[r] = fmaxf(mx[r], mx[r + 4]);
        float b0 = fmaxf(fmaxf(mx[0], mx[2]), fmaxf(mx[1], mx[3]));
        b0 = fmaxf(b0, __shfl_xor(b0, 32, 64));
        bm[cb] = b0;
      }

      // T13 defer-rescale (base-2, THR=8)
      const bool need = (bm[0] - m[0] > 8.0f) || (bm[1] - m[1] > 8.0f);
      if (__any(need)) {
#pragma unroll
        for (int cb = 0; cb < 2; ++cb) {
          const float mnew = fmaxf(m[cb], bm[cb]);
          const float corr = exp2fast(m[cb] - mnew);
          m[cb] = mnew;
          l[cb] *= corr;
#pragma unroll
          for (int ct = 0; ct < 2; ++ct)
#pragma unroll
            for (int r = 0; r < 16; ++r) acc[cb][ct][r] *= corr;
        }
      }

      // p = exp2(s - m) in place; sum; pack via cvt_pk; permlane -> B frags
      short8 pf[2][2];
#pragma unroll
      for (int cb = 0; cb < 2; ++cb) {
#pragma unroll
        for (int r = 0; r < 16; ++r) sacc[cb][r] = exp2fast(sacc[cb][r] - m[cb]);
        float ps[8];
#pragma unroll
        for (int r = 0; r < 8; ++r) ps[r] = sacc[cb][2 * r] + sacc[cb][2 * r + 1];
#pragma unroll
        for (int r = 0; r < 4; ++r) ps[r] += ps[r + 4];
        float psum = (ps[0] + ps[2]) + (ps[1] + ps[3]);
        psum += __shfl_xor(psum, 32, 64);
        l[cb] += psum;

        u32 pk[8];
#pragma unroll
        for (int q2 = 0; q2 < 8; ++q2) {
          const float lo = sacc[cb][2 * q2], hip_ = sacc[cb][2 * q2 + 1];
          asm("v_cvt_pk_bf16_f32 %0, %1, %2" : "=v"(pk[q2]) : "v"(lo), "v"(hip_));
        }
        asm("v_permlane32_swap_b32 %0, %1" : "+v"(pk[0]), "+v"(pk[2]));
        asm("v_permlane32_swap_b32 %0, %1" : "+v"(pk[1]), "+v"(pk[3]));
        asm("v_permlane32_swap_b32 %0, %1" : "+v"(pk[4]), "+v"(pk[6]));
        asm("v_permlane32_swap_b32 %0, %1" : "+v"(pk[5]), "+v"(pk[7]));
        union { u32 u[4]; short8 v; } f0, f1;
        f0.u[0] = pk[0]; f0.u[1] = pk[1]; f0.u[2] = pk[2]; f0.u[3] = pk[3];
        f1.u[0] = pk[4]; f1.u[1] = pk[5]; f1.u[2] = pk[6]; f1.u[3] = pk[7];
        pf[cb][0] = f0.v;
        pf[cb][1] = f1.v;
      }

      // PV: V fragments direct from global/L2, shared across both cbs
#pragma unroll
      for (int ct = 0; ct < 2; ++ct) {
#pragma unroll
        for (int ks2 = 0; ks2 < 2; ++ks2) {
          const short8 vf = *(const short8*)(vbp + (size_t)(ct * 32 + tl) * SEQ +
                                             (s0 + ss * 32 + ks2 * 16 + hi * 8));
          acc[0][ct] = __builtin_amdgcn_mfma_f32_32x32x16_bf16(vf, pf[0][ks2], acc[0][ct], 0, 0, 0);
          acc[1][ct] = __builtin_amdgcn_mfma_f32_32x32x16_bf16(vf, pf[1][ks2], acc[1][ct], 0, 0, 0);
        }
      }
    }
  }

  // ---- merge the two s-halves via LDS, then store ----
  if (sh == 1) {
    float* Xa = &Xacc[unit][0];
#pragma unroll
    for (int cb = 0; cb < 2; ++cb) {
      Xml[unit][cb][0][tl] = m[cb];
      Xml[unit][cb][1][tl] = l[cb];
#pragma unroll
      for (int ct = 0; ct < 2; ++ct)
#pragma unroll
        for (int r = 0; r < 16; ++r)
          Xa[((cb * 2 + ct) * 16 + r) * 64 + lane] = acc[cb][ct][r];
    }
  }
  __syncthreads();
  if (sh == 0) {
    const float* Xa = &Xacc[unit][0];
    float* ob = out + (size_t)bh * 64 * SEQ;
#pragma unroll
    for (int cb = 0; cb < 2; ++cb) {
      const float mb = Xml[unit][cb][0][tl];
      const float lb = Xml[unit][cb][1][tl];
      const float M = fmaxf(m[cb], mb);
      const float fa = exp2fast(m[cb] - M);
      const float fb = exp2fast(mb - M);
      const float inv = 1.0f / (l[cb] * fa + lb * fb);
      const int t = tq0 + cb * 32 + tl;
#pragma unroll
      for (int ct = 0; ct < 2; ++ct)
#pragma unroll
        for (int r = 0; r < 16; ++r) {
          const int c = ct * 32 + (r & 3) + 8 * (r >> 2) + 4 * hi;
          const float o = (acc[cb][ct][r] * fa + Xa[((cb * 2 + ct) * 16 + r) * 64 + lane] * fb) * inv;
          ob[(size_t)c * SEQ + t] = o;
        }
    }
  }
}

extern "C" void kernel_launch(void* const* d_in, const int* in_sizes, int n_in,
                              void* d_out, int out_size, void* d_ws, size_t ws_size,
                              hipStream_t stream) {
  const float* qkv = (const float*)d_in[0];
  float* out = (float*)d_out;
  u16* wsQ = (u16*)d_ws;
  u16* wsK = wsQ + (size_t)32 * SEQ * 64;
  u16* wsV = wsK + (size_t)32 * SEQ * 64;

  prep_qk<<<dim3(32, 32, 2), 256, 0, stream>>>(qkv, wsQ, wsK);
  prep_v<<<4096, 256, 0, stream>>>(qkv, wsV);
  attn_kernel<<<512, 256, 0, stream>>>(wsQ, wsK, wsV, out);
}